// Round 4
// baseline (709.216 us; speedup 1.0000x reference)
//
#include <hip/hip_runtime.h>
#include <hip/hip_cooperative_groups.h>
#include <math.h>

namespace cg = cooperative_groups;

#define NROWS 6144
#define LSIG  5000
#define NT    256

// db4 decomposition filters (natural order), hi[k] = (-1)^(k+1) lo[k]
#define DL0 (-0.010597401784997278f)
#define DL1 ( 0.032883011666982945f)
#define DL2 ( 0.030841381835986965f)
#define DL3 (-0.18703481171888114f)
#define DL4 (-0.02798376941698385f)
#define DL5 ( 0.6308807679295904f)
#define DL6 ( 0.7148465705525415f)
#define DL7 ( 0.23037781330885523f)
#define DH0 ( 0.010597401784997278f)
#define DH1 ( 0.032883011666982945f)
#define DH2 (-0.030841381835986965f)
#define DH3 (-0.18703481171888114f)
#define DH4 ( 0.02798376941698385f)
#define DH5 ( 0.6308807679295904f)
#define DH6 (-0.7148465705525415f)
#define DH7 ( 0.23037781330885523f)

// Forward DWT (edge path): ca[k] = sum_t xp[2k+t]*lo[7-t].
// xp index map (reflect pad 7,7 drop first): j=2k+t-6; i=|j|; if i>=L -> 2L-2-i
__device__ __forceinline__ void dwt_pair_edge(const float* __restrict__ src, int L, int k,
                                              float& a, float& b) {
    const float LO[8] = {DL0,DL1,DL2,DL3,DL4,DL5,DL6,DL7};
    const float HI[8] = {DH0,DH1,DH2,DH3,DH4,DH5,DH6,DH7};
    a = 0.f; b = 0.f;
    int base = 2*k - 6;
#pragma unroll
    for (int t = 0; t < 8; ++t) {
        int j = base + t;
        int i = (j < 0) ? -j : j;
        if (i >= L) i = 2*L - 2 - i;
        float v = src[i];
        a += v * LO[7-t];
        b += v * HI[7-t];
    }
}

// Interior fast path: valid when k>=3 && 2k+1 <= L-1
__device__ __forceinline__ void dwt_pair_int(const float* __restrict__ src, int k,
                                             float& a, float& b) {
    int base = 2*k - 6;
    float v0 = src[base],     v1 = src[base + 1], v2 = src[base + 2], v3 = src[base + 3];
    float v4 = src[base + 4], v5 = src[base + 5], v6 = src[base + 6], v7 = src[base + 7];
    a = v0*DL7 + v1*DL6 + v2*DL5 + v3*DL4 + v4*DL3 + v5*DL2 + v6*DL1 + v7*DL0;
    b = v0*DH7 + v1*DH6 + v2*DH5 + v3*DH4 + v4*DH3 + v5*DH2 + v6*DH1 + v7*DH0;
}

// Pair-form lowpass-only inverse: outputs o=2m / o=2m+1 share ca[m..m+3].
__device__ __forceinline__ void idwt_lo_pair(const float* __restrict__ ca, int m,
                                             float& ev, float& od) {
    float c0 = ca[m], c1 = ca[m+1], c2 = ca[m+2], c3 = ca[m+3];
    ev = c0*DL1 + c1*DL3 + c2*DL5 + c3*DL7;
    od = c0*DL0 + c1*DL2 + c2*DL4 + c3*DL6;
}

// ---------------- Kernel A: baseline removal + forward 4-level DWT ----------------
// Arena live-range plan (floats):
//   sig0 @[0,5000) only until level-0 transform (x re-read from global at subtract)
//   sigs[1]@5000(2503); sigs[2..8]@{0,1255,1886,2205,2368,2453,2499}
//   recon dst: k odd -> @5000 (k=1 len 2503 fits), k even -> @2525 (len<=1255)
//   residual @[0,5000); phase2 lp: L0->@5000, L1->@0, L2->@1255, L3->global direct
// LDS ~30.2 KB -> 5 blocks/CU.
__global__ __launch_bounds__(NT, 5) void kernelA(const float* __restrict__ x,
                                                 float* __restrict__ g_d1, float* __restrict__ g_d2,
                                                 float* __restrict__ g_d3, float* __restrict__ g_d4,
                                                 float* __restrict__ g_ca4,
                                                 unsigned* __restrict__ bins_all) {
    __shared__ float S[7503];
    __shared__ float redm[9][4];
    __shared__ int depth_s;

    const int row = blockIdx.x;
    const int tid = threadIdx.x;

    // zero median bins (2048+2048+1024 u32) from the first 20 blocks
    if (blockIdx.x < 20) bins_all[blockIdx.x * NT + tid] = 0u;

    {
        const float4* xr4 = (const float4*)(x + (size_t)row * LSIG);
        float4* s4 = (float4*)S;
        for (int i = tid; i < 1250; i += NT) s4[i] = xr4[i];
    }
    __syncthreads();

    const int lensA[10]    = {5000, 2503, 1255, 631, 319, 163, 85, 46, 26, 16};
    const int sigs_off[9]  = {0, 5000, 0, 1255, 1886, 2205, 2368, 2453, 2499};

    // ---- phase 1: pyramid; per-thread SSD accumulators (t=8 lowpass discarded) ----
    float sp[9];
#pragma unroll
    for (int t = 0; t < 9; ++t) {
        const int L   = lensA[t];
        const int Lo  = lensA[t + 1];
        const int kHi = (L - 2) >> 1;
        const float* src = S + sigs_off[t];
        float* lp = (t < 8) ? (S + sigs_off[t + 1]) : (float*)nullptr;
        float part = 0.f;
        for (int k = tid; k < Lo; k += NT) {
            float a, b;
            if (k >= 3 && k <= kHi) dwt_pair_int(src, k, a, b);
            else                    dwt_pair_edge(src, L, k, a, b);
            if (t < 8) lp[k] = a;
            part += b * b;
        }
        sp[t] = part;
        __syncthreads();
    }

    // ---- one reduction for all 9 SSDs, then depth decision ----
#pragma unroll
    for (int t = 0; t < 9; ++t) {
        float p = sp[t];
#pragma unroll
        for (int o = 32; o; o >>= 1) p += __shfl_down(p, o, 64);
        if ((tid & 63) == 0) redm[t][tid >> 6] = p;
    }
    __syncthreads();
    if (tid == 0) {
        float ssds[9];
#pragma unroll
        for (int t = 0; t < 9; ++t) ssds[t] = redm[t][0] + redm[t][1] + redm[t][2] + redm[t][3];
        int dd = -1;
        for (int t = 2; t <= 8; ++t)
            if (dd < 0 && ssds[t - 2] > ssds[t - 1] && ssds[t - 1] < ssds[t]) dd = t;
        depth_s = (dd < 0) ? 8 : dd;
    }
    __syncthreads();
    const int d = depth_s;   // in [2,8]

    // ---- baseline recon: (idwt_lo)^d of sigs[d]; final (k=1) always lands @5000 ----
    const float* cur = S + sigs_off[d];
    for (int k = d - 1; k >= 1; --k) {
        const int ol = lensA[k];
        float* dst = S + ((k & 1) ? 5000 : 2525);
        const int np = (ol + 1) >> 1;
        for (int m = tid; m < np; m += NT) {
            float ev, od;
            idwt_lo_pair(cur, m, ev, od);
            dst[2*m] = ev;
            if (2*m + 1 < ol) dst[2*m + 1] = od;
        }
        __syncthreads();
        cur = dst;
    }
    // subtract: re-read x (L2-warm), residual -> S[0,5000)
    {
        const float2* x2 = (const float2*)(x + (size_t)row * LSIG);
        for (int m = tid; m < 2500; m += NT) {
            float ev, od;
            idwt_lo_pair(cur, m, ev, od);   // cur @5000, len 2503
            float2 xv = x2[m];
            S[2*m]     = xv.x - ev;
            S[2*m + 1] = xv.y - od;
        }
    }
    __syncthreads();

    // ---- phase 2: 4-level forward DWT of residual ----
    const int l2[5] = {5000, 2503, 1255, 631, 319};
    const int srcoff[4] = {0, 5000, 0, 1255};
    const int dstoff[4] = {5000, 0, 1255, 0 /*unused*/};
#pragma unroll
    for (int lev = 0; lev < 4; ++lev) {
        const int L   = l2[lev];
        const int Lo  = l2[lev + 1];
        const int kHi = (L - 2) >> 1;
        const float* src = S + srcoff[lev];
        float* lp = S + dstoff[lev];
        float* hg;
        if      (lev == 0) hg = g_d1 + (size_t)row * 2503;
        else if (lev == 1) hg = g_d2 + (size_t)row * 1255;
        else if (lev == 2) hg = g_d3 + (size_t)row * 631;
        else               hg = g_d4 + (size_t)row * 319;
        float* cg = g_ca4 + (size_t)row * 319;
        for (int k = tid; k < Lo; k += NT) {
            float a, b;
            if (k >= 3 && k <= kHi) dwt_pair_int(src, k, a, b);
            else                    dwt_pair_edge(src, L, k, a, b);
            if (lev < 3) lp[k] = a;
            else         cg[k] = a;     // level 3: ca4 straight to global
            hg[k] = b;
        }
        __syncthreads();
    }
}

// ---------------- fused cooperative median (radix-select, 3 passes) ----------------
__device__ __forceinline__ void select_in_lds(unsigned* h, int nb, int shift,
                                              unsigned prefix_in, unsigned krem_in,
                                              unsigned* state, float* sigma_out,
                                              int final_pass, int tid) {
    if (tid < 64) {
        const int sl = nb >> 6;
        const int base = tid * sl;
        unsigned s = 0;
        for (int j = 0; j < sl; ++j) s += h[base + j];
        unsigned c = s;
#pragma unroll
        for (int o = 1; o < 64; o <<= 1) {
            unsigned t = __shfl_up(c, o, 64);
            if (tid >= o) c += t;
        }
        unsigned long long m = __ballot(c > krem_in);
        int tseg = __ffsll(m) - 1;
        if (tid == tseg) {
            unsigned cum = c - s;       // exclusive prefix of target segment
            int b = base;
            for (int j = 0; j < sl; ++j) {
                unsigned cc = h[base + j];
                if (cum + cc > krem_in) { b = base + j; break; }
                cum += cc;
            }
            unsigned pref = prefix_in | ((unsigned)b << shift);
            __hip_atomic_store(&state[0], pref, __ATOMIC_RELEASE, __HIP_MEMORY_SCOPE_AGENT);
            __hip_atomic_store(&state[1], krem_in - cum, __ATOMIC_RELEASE, __HIP_MEMORY_SCOPE_AGENT);
            if (final_pass) *sigma_out = __uint_as_float(pref) / 0.6745f;
        }
    }
}

__global__ __launch_bounds__(NT) void kmedian(const float* __restrict__ d4, int n,
                                              unsigned* __restrict__ bins0,
                                              unsigned* __restrict__ bins1,
                                              unsigned* __restrict__ bins2,
                                              unsigned* __restrict__ state,
                                              float* __restrict__ sigma_out) {
    cg::grid_group grid = cg::this_grid();
    __shared__ unsigned h[2048];
    const int tid = threadIdx.x;
    const int gsz = (int)gridDim.x * NT;
    const int gid = (int)blockIdx.x * NT + tid;

    // ---- pass 0: bits 31..21 ----
    for (int i = tid; i < 2048; i += NT) h[i] = 0u;
    __syncthreads();
    for (int i = gid; i < n; i += gsz)
        atomicAdd(&h[__float_as_uint(fabsf(d4[i])) >> 21], 1u);
    __syncthreads();
    for (int i = tid; i < 2048; i += NT) if (h[i]) atomicAdd(&bins0[i], h[i]);
    grid.sync();
    if (blockIdx.x == 0) {
        for (int i = tid; i < 2048; i += NT) h[i] = bins0[i];
        __syncthreads();
        select_in_lds(h, 2048, 21, 0u, 979967u, state, sigma_out, 0, tid);  // k=(1959936-1)/2
    }
    grid.sync();

    // ---- pass 1: bits 20..10 ----
    unsigned pref = __hip_atomic_load(&state[0], __ATOMIC_ACQUIRE, __HIP_MEMORY_SCOPE_AGENT);
    unsigned krem = __hip_atomic_load(&state[1], __ATOMIC_ACQUIRE, __HIP_MEMORY_SCOPE_AGENT);
    for (int i = tid; i < 2048; i += NT) h[i] = 0u;
    __syncthreads();
    for (int i = gid; i < n; i += gsz) {
        unsigned key = __float_as_uint(fabsf(d4[i]));
        if ((key & 0xFFE00000u) == pref) atomicAdd(&h[(key >> 10) & 2047u], 1u);
    }
    __syncthreads();
    for (int i = tid; i < 2048; i += NT) if (h[i]) atomicAdd(&bins1[i], h[i]);
    grid.sync();
    if (blockIdx.x == 0) {
        for (int i = tid; i < 2048; i += NT) h[i] = bins1[i];
        __syncthreads();
        select_in_lds(h, 2048, 10, pref, krem, state, sigma_out, 0, tid);
    }
    grid.sync();

    // ---- pass 2: bits 9..0 ----
    pref = __hip_atomic_load(&state[0], __ATOMIC_ACQUIRE, __HIP_MEMORY_SCOPE_AGENT);
    krem = __hip_atomic_load(&state[1], __ATOMIC_ACQUIRE, __HIP_MEMORY_SCOPE_AGENT);
    for (int i = tid; i < 1024; i += NT) h[i] = 0u;
    __syncthreads();
    for (int i = gid; i < n; i += gsz) {
        unsigned key = __float_as_uint(fabsf(d4[i]));
        if ((key & 0xFFFFFC00u) == pref) atomicAdd(&h[key & 1023u], 1u);
    }
    __syncthreads();
    for (int i = tid; i < 1024; i += NT) if (h[i]) atomicAdd(&bins2[i], h[i]);
    grid.sync();
    if (blockIdx.x == 0) {
        for (int i = tid; i < 1024; i += NT) h[i] = bins2[i];
        __syncthreads();
        select_in_lds(h, 1024, 0, pref, krem, state, sigma_out, 1, tid);
    }
}

// ---------------- Kernel C: threshold + inverse DWT + normalize ----------------
// Dd eliminated: detail coeffs thresholded inline from global (L1/L2 absorb 4x reuse).
// LDS ~30.1 KB -> 5 blocks/CU.
__device__ __forceinline__ void idwt_pair_g(const float* __restrict__ ca,
                                            const float* __restrict__ dg, float sigma,
                                            int m, float& ev, float& od) {
    float c0 = ca[m], c1 = ca[m+1], c2 = ca[m+2], c3 = ca[m+3];
    float e0 = dg[m],   e1 = dg[m+1], e2 = dg[m+2], e3 = dg[m+3];
    e0 = (e0 < sigma) ? 0.f : e0;
    e1 = (e1 < sigma) ? 0.f : e1;
    e2 = (e2 < sigma) ? 0.f : e2;
    e3 = (e3 < sigma) ? 0.f : e3;
    ev = c0*DL1 + c1*DL3 + c2*DL5 + c3*DL7 + e0*DH1 + e1*DH3 + e2*DH5 + e3*DH7;
    od = c0*DL0 + c1*DL2 + c2*DL4 + c3*DL6 + e0*DH0 + e1*DH2 + e2*DH4 + e3*DH6;
}

__global__ __launch_bounds__(NT, 5) void kernelC(const float* __restrict__ g_d1,
                                                 const float* __restrict__ g_d2,
                                                 const float* __restrict__ g_d3,
                                                 const float* __restrict__ g_d4,
                                                 const float* __restrict__ g_ca4,
                                                 const float* __restrict__ sigma_p,
                                                 float* __restrict__ out) {
    __shared__ float A[5000];
    __shared__ float B[2504];
    __shared__ double redd[4][2];
    __shared__ float sg;

    const int row = blockIdx.x;
    const int tid = threadIdx.x;
    if (tid == 0) sg = *sigma_p;
    for (int i = tid; i < 319; i += NT) A[i] = g_ca4[(size_t)row * 319 + i];
    __syncthreads();
    const float sigma = sg;

    const int Cs[4] = {319, 631, 1255, 2503};
    const int Os[4] = {632, 1256, 2504, 5000};

#pragma unroll
    for (int s = 0; s < 4; ++s) {
        const int C = Cs[s];
        const int O = Os[s];
        const float* dg;
        if      (s == 0) dg = g_d4 + (size_t)row * 319;
        else if (s == 1) dg = g_d3 + (size_t)row * 631;
        else if (s == 2) dg = g_d2 + (size_t)row * 1255;
        else             dg = g_d1 + (size_t)row * 2503;
        const float* spb = (s & 1) ? B : A;
        float* dp        = (s & 1) ? A : B;
        const int np = O >> 1;               // O always even
        (void)C;
        for (int m = tid; m < np; m += NT) {
            float ev, od;
            idwt_pair_g(spb, dg, sigma, m, ev, od);
            dp[2*m]     = ev;
            dp[2*m + 1] = od;
        }
        __syncthreads();
    }

    // normalize A[0..4999]: single-pass sum/sumsq in double, std(ddof=1), nan_to_num
    double s1 = 0.0, s2 = 0.0;
    for (int i = tid; i < 5000; i += NT) {
        double v = (double)A[i];
        s1 += v;
        s2 += v * v;
    }
#pragma unroll
    for (int o = 32; o; o >>= 1) {
        s1 += __shfl_down(s1, o, 64);
        s2 += __shfl_down(s2, o, 64);
    }
    if ((tid & 63) == 0) { redd[tid >> 6][0] = s1; redd[tid >> 6][1] = s2; }
    __syncthreads();
    double sum  = redd[0][0] + redd[1][0] + redd[2][0] + redd[3][0];
    double sumq = redd[0][1] + redd[1][1] + redd[2][1] + redd[3][1];
    double mean = sum / 5000.0;
    double var  = (sumq - sum * mean) / 4999.0;

    float meanf = (float)mean;
    float inv = 1.0f / (float)sqrt(var);
    float* orow = out + (size_t)row * 5000;
    for (int i = tid; i < 5000; i += NT) {
        float r = (A[i] - meanf) * inv;
        if (isnan(r)) r = 0.f;
        else if (isinf(r)) r = copysignf(3.4028234663852886e38f, r);
        orow[i] = r;
    }
}

extern "C" void kernel_launch(void* const* d_in, const int* in_sizes, int n_in,
                              void* d_out, int out_size, void* d_ws, size_t ws_size,
                              hipStream_t stream) {
    const float* x = (const float*)d_in[0];
    float* out = (float*)d_out;

    const size_t n1 = (size_t)NROWS * 2503;
    const size_t n2 = (size_t)NROWS * 1255;
    const size_t n3 = (size_t)NROWS * 631;
    const size_t n4 = (size_t)NROWS * 319;

    float* w    = (float*)d_ws;
    float* d1   = w;
    float* d2   = d1 + n1;
    float* d3   = d2 + n2;
    float* d4   = d3 + n3;
    float* ca4  = d4 + n4;
    unsigned* bins0 = (unsigned*)(ca4 + n4);   // 2048
    unsigned* bins1 = bins0 + 2048;            // 2048
    unsigned* bins2 = bins1 + 2048;            // 1024
    unsigned* state = bins2 + 1024;            // 2
    float* sigp = (float*)(state + 2);
    int n = (int)n4;  // 1,959,936

    hipLaunchKernelGGL(kernelA, dim3(NROWS), dim3(NT), 0, stream,
                       x, d1, d2, d3, d4, ca4, bins0);

    {
        const float* d4c = d4;
        void* args[] = {(void*)&d4c, (void*)&n, (void*)&bins0, (void*)&bins1,
                        (void*)&bins2, (void*)&state, (void*)&sigp};
        hipLaunchCooperativeKernel((void*)kmedian, dim3(512), dim3(NT), args, 0, stream);
    }

    hipLaunchKernelGGL(kernelC, dim3(NROWS), dim3(NT), 0, stream,
                       d1, d2, d3, d4, ca4, sigp, out);
}